// Round 1
// baseline (213.988 us; speedup 1.0000x reference)
//
#include <hip/hip_runtime.h>
#include <hip/hip_bf16.h>

// Problem constants
#define B_   8
#define LE_  4096
#define LD_  4096
#define DE_  512
#define AA_  128
#define RTOT (B_*LE_)      // 32768 encoder rows
#define NDIM 256           // k(128) | v(128) fused output cols
#define KDIM 512
#define BM   64
#define BK   64
#define LDSS 72            // LDS row stride in bf16 elems (64 + 8 pad)

typedef __attribute__((ext_vector_type(8))) short short8;
typedef __attribute__((ext_vector_type(4))) float f32x4;

// ---- workspace layout (bytes) ----
#define WCT_OFF   0                         // ushort[256][512] = 262144
#define U_OFF     262144                    // float[128]       = 512
#define BIAS_OFF  262656                    // float[256]       = 1024
#define NUM_OFF   263680                    // float[8*128]     = 4096
#define RS_OFF    267776                    // float[8]         = 32 (pad to 64)
#define KT_OFF    267840                    // float[32768]     = 131072
#define WW_OFF    398912                    // float[32768]     = 131072
#define C_OFF     529984                    // float[32768*256] = 33554432
// total ~34.1 MB

__device__ inline ushort f2bf(float f) {
    union { float f; unsigned u; } x; x.f = f;
    unsigned r = x.u + 0x7fffu + ((x.u >> 16) & 1u);  // RNE
    return (ushort)(r >> 16);
}

// ---------------- prep: WcT (transposed bf16 weights), bias, u = Pu@pv, zero num
__global__ void prep_kernel(const float* __restrict__ Wk, const float* __restrict__ bk,
                            const float* __restrict__ Wv, const float* __restrict__ bv,
                            const float* __restrict__ Pu, const float* __restrict__ pv,
                            ushort* __restrict__ wct, float* __restrict__ u,
                            float* __restrict__ bias, float* __restrict__ num) {
    int t = threadIdx.x;
    int base = blockIdx.x * 256 + t;
    // WcT[n][k]: 256*512 elems, grid 128 x 256 -> 4 per thread
    for (int i = 0; i < 4; ++i) {
        int idx = base + i * 32768;
        int n = idx >> 9, k = idx & 511;
        float s = (n < 128) ? Wk[k * 128 + n] : Wv[k * 128 + (n - 128)];
        wct[idx] = f2bf(s);
    }
    if (blockIdx.x == 0) {
        if (t < 128) {
            float acc = 0.f;
            for (int c = 0; c < 128; ++c) acc += Pu[t * 128 + c] * pv[c];
            u[t] = acc;
        }
        bias[t] = (t < 128) ? bk[t] : bv[t - 128];
        for (int i = 0; i < 4; ++i) num[t + i * 256] = 0.f;
    }
}

// ---------------- main GEMM: C[r][0:256] = relu(enc[r,:] @ [Wk|Wv] + [bk|bv])
__global__ __launch_bounds__(256)
void gemm_kernel(const float* __restrict__ enc, const ushort* __restrict__ wct,
                 const float* __restrict__ bias, float* __restrict__ C) {
    __shared__ ushort As[BM][LDSS];     //  9216 B
    __shared__ ushort Bs[NDIM][LDSS];   // 36864 B
    const int t = threadIdx.x;
    const int wv = t >> 6, l = t & 63;
    const int m = l & 15, kb = l >> 4;
    const int row0 = blockIdx.x * BM;

    f32x4 acc[4][4] = {};

    for (int k0 = 0; k0 < KDIM; k0 += BK) {
        // stage A: 64 rows x 64 k, f32 -> bf16, 8 elems/chunk, 512 chunks
#pragma unroll
        for (int i = 0; i < 2; ++i) {
            int c = t + i * 256;
            int r = c >> 3, k8 = (c & 7) * 8;
            const float4* src = (const float4*)(enc + (size_t)(row0 + r) * KDIM + k0 + k8);
            float4 a0 = src[0], a1 = src[1];
            int4 pk;
            pk.x = (int)f2bf(a0.x) | ((int)f2bf(a0.y) << 16);
            pk.y = (int)f2bf(a0.z) | ((int)f2bf(a0.w) << 16);
            pk.z = (int)f2bf(a1.x) | ((int)f2bf(a1.y) << 16);
            pk.w = (int)f2bf(a1.z) | ((int)f2bf(a1.w) << 16);
            *(int4*)&As[r][k8] = pk;
        }
        // stage B: 256 n x 64 k bf16 from transposed weights, 2048 chunks
#pragma unroll
        for (int i = 0; i < 8; ++i) {
            int c = t + i * 256;
            int n = c >> 3, k8 = (c & 7) * 8;
            int4 v = *(const int4*)(wct + (size_t)n * KDIM + k0 + k8);
            *(int4*)&Bs[n][k8] = v;
        }
        __syncthreads();
#pragma unroll
        for (int kc = 0; kc < 2; ++kc) {
            short8 afr[4], bfr[4];
#pragma unroll
            for (int mt = 0; mt < 4; ++mt)
                afr[mt] = *(const short8*)&As[mt * 16 + m][kc * 32 + kb * 8];
#pragma unroll
            for (int nt = 0; nt < 4; ++nt)
                bfr[nt] = *(const short8*)&Bs[wv * 64 + nt * 16 + m][kc * 32 + kb * 8];
#pragma unroll
            for (int mt = 0; mt < 4; ++mt)
#pragma unroll
                for (int nt = 0; nt < 4; ++nt)
                    acc[mt][nt] = __builtin_amdgcn_mfma_f32_16x16x32_bf16(
                        afr[mt], bfr[nt], acc[mt][nt], 0, 0, 0);
        }
        __syncthreads();
    }
    // epilogue: bias + relu, store f32
    const int rgrp = l >> 4;
#pragma unroll
    for (int mt = 0; mt < 4; ++mt) {
#pragma unroll
        for (int nt = 0; nt < 4; ++nt) {
            int col = wv * 64 + nt * 16 + (l & 15);
            float bsv = bias[col];
#pragma unroll
            for (int r = 0; r < 4; ++r) {
                int rowl = mt * 16 + rgrp * 4 + r;
                float v = acc[mt][nt][r] + bsv;
                C[(size_t)(row0 + rowl) * NDIM + col] = v > 0.f ? v : 0.f;
            }
        }
    }
}

// ---------------- kt[r] = C[r,0:128] . u  (one wave per row)
__global__ void kt_kernel(const float* __restrict__ C, const float* __restrict__ u,
                          float* __restrict__ kt) {
    int gid = blockIdx.x * 256 + threadIdx.x;
    int r = gid >> 6, l = gid & 63;
    float a = C[(size_t)r * NDIM + l] * u[l] + C[(size_t)r * NDIM + 64 + l] * u[64 + l];
#pragma unroll
    for (int off = 32; off > 0; off >>= 1) a += __shfl_down(a, off);
    if (l == 0) kt[r] = a;
}

// ---------------- per-batch softmax over 4096 kt values
__global__ __launch_bounds__(1024)
void softmax_kernel(const float* __restrict__ kt, float* __restrict__ w,
                    float* __restrict__ rS) {
    __shared__ float red[1024];
    int b = blockIdx.x, t = threadIdx.x;
    const float inv_s = 0.08838834764831843f;  // 1/sqrt(128)
    float v[4], m = -1e30f;
#pragma unroll
    for (int i = 0; i < 4; ++i) {
        v[i] = kt[b * 4096 + i * 1024 + t];
        m = fmaxf(m, v[i]);
    }
    red[t] = m; __syncthreads();
    for (int off = 512; off > 0; off >>= 1) {
        if (t < off) red[t] = fmaxf(red[t], red[t + off]);
        __syncthreads();
    }
    float M = red[0]; __syncthreads();
    float s = 0.f;
#pragma unroll
    for (int i = 0; i < 4; ++i) {
        float e = __expf((v[i] - M) * inv_s);
        w[b * 4096 + i * 1024 + t] = e;
        s += e;
    }
    red[t] = s; __syncthreads();
    for (int off = 512; off > 0; off >>= 1) {
        if (t < off) red[t] += red[t + off];
        __syncthreads();
    }
    if (t == 0) rS[b] = 1.0f / red[0];
}

// ---------------- num[b,d] = sum_j w[b,j] * v[b,j,d]   (v = C cols 128..255)
__global__ void wsum_kernel(const float* __restrict__ C, const float* __restrict__ w,
                            float* __restrict__ num) {
    int b = blockIdx.x >> 4, ch = blockIdx.x & 15;
    int t = threadIdx.x;
    int d = t & 127, jj = t >> 7;
    size_t base_row = (size_t)b * 4096 + ch * 256;
    float acc = 0.f;
    for (int j = jj; j < 256; j += 2) {
        size_t r = base_row + j;
        acc += w[r] * C[r * NDIM + 128 + d];
    }
    atomicAdd(&num[b * 128 + d], acc);
}

// ---------------- broadcast: out[b,i,d] = num[b,d] * rS[b]
__global__ void bcast_kernel(const float* __restrict__ num, const float* __restrict__ rS,
                             float4* __restrict__ out) {
    int g = blockIdx.x * 256 + threadIdx.x;
    const float4* n4 = (const float4*)num;
    const int total4 = B_ * LD_ * AA_ / 4;  // 1048576
    for (int c = g; c < total4; c += 262144) {
        int flat = c * 4;
        int b = flat >> 19;          // / (4096*128)
        int d = flat & 127;
        float4 nv = n4[b * 32 + (d >> 2)];
        float s = rS[b];
        float4 o;
        o.x = nv.x * s; o.y = nv.y * s; o.z = nv.z * s; o.w = nv.w * s;
        out[c] = o;
    }
}

extern "C" void kernel_launch(void* const* d_in, const int* in_sizes, int n_in,
                              void* d_out, int out_size, void* d_ws, size_t ws_size,
                              hipStream_t stream) {
    const float* enc = (const float*)d_in[0];
    // d_in[1]=decoder, d_in[2]=Wq, d_in[3]=bq, d_in[8]=Pw: provably unused (softmax shift-invariance)
    const float* Wk = (const float*)d_in[4];
    const float* bk = (const float*)d_in[5];
    const float* Wv = (const float*)d_in[6];
    const float* bv = (const float*)d_in[7];
    const float* Pu = (const float*)d_in[9];
    const float* pv = (const float*)d_in[10];

    char* ws = (char*)d_ws;
    ushort* wct  = (ushort*)(ws + WCT_OFF);
    float*  u    = (float*)(ws + U_OFF);
    float*  bias = (float*)(ws + BIAS_OFF);
    float*  num  = (float*)(ws + NUM_OFF);
    float*  rS   = (float*)(ws + RS_OFF);
    float*  kt   = (float*)(ws + KT_OFF);
    float*  w    = (float*)(ws + WW_OFF);
    float*  C    = (float*)(ws + C_OFF);

    prep_kernel<<<128, 256, 0, stream>>>(Wk, bk, Wv, bv, Pu, pv, wct, u, bias, num);
    gemm_kernel<<<RTOT / BM, 256, 0, stream>>>(enc, wct, bias, C);
    kt_kernel<<<RTOT / 4, 256, 0, stream>>>(C, u, kt);
    softmax_kernel<<<B_, 1024, 0, stream>>>(kt, w, rS);
    wsum_kernel<<<B_ * 16, 256, 0, stream>>>(C, w, num);
    bcast_kernel<<<1024, 256, 0, stream>>>(num, rS, (float4*)d_out);
}

// Round 3
// 184.053 us; speedup vs baseline: 1.1626x; 1.1626x over previous
//
#include <hip/hip_runtime.h>
#include <hip/hip_bf16.h>

// Problem constants
#define B_   8
#define LE_  4096
#define LD_  4096
#define KDIM 512
#define AA_  128
#define RTOT (B_*LE_)      // 32768 encoder rows
#define NDIM 256           // k(128) | v(128) fused output cols

typedef __attribute__((ext_vector_type(8))) short short8;
typedef __attribute__((ext_vector_type(4))) float f32x4;

// ---- workspace layout (bytes) ----
#define WCT_OFF   0                         // ushort[256][512] = 262144
#define U_OFF     262144                    // float[128]       = 512
#define BIAS_OFF  262656                    // float[256]       = 1024
#define NUM_OFF   263680                    // float[8*128]     = 4096
#define S_OFF     267776                    // float[32768]     = 131072  (raw scores)
#define WN_OFF    398848                    // float[32768]     = 131072  (normalized weights)
#define VB_OFF    529920                    // ushort[32768*128]= 8388608 (v, bf16)
// total ~8.9 MB

__device__ inline ushort f2bf(float f) {
    union { float f; unsigned u; } x; x.f = f;
    unsigned r = x.u + 0x7fffu + ((x.u >> 16) & 1u);  // RNE
    return (ushort)(r >> 16);
}
__device__ inline float bf2f(ushort s) {
    union { unsigned u; float f; } x; x.u = ((unsigned)s) << 16;
    return x.f;
}

// ---------------- prep: WcT (transposed bf16 weights), bias, u = Pu@pv, zero num
__global__ void prep_kernel(const float* __restrict__ Wk, const float* __restrict__ bk,
                            const float* __restrict__ Wv, const float* __restrict__ bv,
                            const float* __restrict__ Pu, const float* __restrict__ pv,
                            ushort* __restrict__ wct, float* __restrict__ u,
                            float* __restrict__ bias, float* __restrict__ num) {
    int t = threadIdx.x;
    int base = blockIdx.x * 256 + t;
    // WcT[n][k]: 256*512 elems, grid 128 x 256 -> 4 per thread
    for (int i = 0; i < 4; ++i) {
        int idx = base + i * 32768;
        int n = idx >> 9, k = idx & 511;
        float s = (n < 128) ? Wk[k * 128 + n] : Wv[k * 128 + (n - 128)];
        wct[idx] = f2bf(s);
    }
    if (blockIdx.x == 0) {
        if (t < 128) {
            float acc = 0.f;
            for (int c = 0; c < 128; ++c) acc += Pu[t * 128 + c] * pv[c];
            u[t] = acc;
        }
        bias[t] = (t < 128) ? bk[t] : bv[t - 128];
        for (int i = 0; i < 4; ++i) num[t + i * 256] = 0.f;
    }
}

// ---------------- fused GEMM:
//   kv[r][0:256] = relu(enc[r,:] @ [Wk|Wv] + [bk|bv])
//   s[r]  = kv[r][0:128] . u          (epilogue, in-register)
//   vbuf[r][0:128] = bf16(kv[r][128:256])
__global__ __launch_bounds__(512, 4)
void gemm_fused(const float* __restrict__ enc, const ushort* __restrict__ wct,
                const float* __restrict__ bias, const float* __restrict__ u,
                ushort* __restrict__ vbuf, float* __restrict__ sout) {
    __shared__ ushort As[64][72];       //  9216 B
    __shared__ ushort Bs[256][72];      // 36864 B
    __shared__ float s_red[64][2];      //   512 B
    const int t = threadIdx.x;
    const int wv = t >> 6, l = t & 63;
    const int wm = wv >> 2, wn = wv & 3;     // wave grid 2(m) x 4(n)
    const int m = l & 15, kb = l >> 4;
    const int row0 = blockIdx.x * 64;

    f32x4 acc[2][4] = {};

    for (int k0 = 0; k0 < KDIM; k0 += 64) {
        // stage A: 64 rows x 64 k, f32 -> bf16; 512 chunks of 8, one per thread
        {
            int r = t >> 3, k8 = (t & 7) * 8;
            const float4* src = (const float4*)(enc + (size_t)(row0 + r) * KDIM + k0 + k8);
            float4 a0 = src[0], a1 = src[1];
            int4 pk;
            pk.x = (int)f2bf(a0.x) | ((int)f2bf(a0.y) << 16);
            pk.y = (int)f2bf(a0.z) | ((int)f2bf(a0.w) << 16);
            pk.z = (int)f2bf(a1.x) | ((int)f2bf(a1.y) << 16);
            pk.w = (int)f2bf(a1.z) | ((int)f2bf(a1.w) << 16);
            *(int4*)&As[r][k8] = pk;
        }
        // stage B: 256 n x 64 k bf16; 2048 chunks, 4 per thread
#pragma unroll
        for (int i = 0; i < 4; ++i) {
            int c = t + i * 512;
            int n = c >> 3, k8 = (c & 7) * 8;
            *(int4*)&Bs[n][k8] = *(const int4*)(wct + (size_t)n * KDIM + k0 + k8);
        }
        __syncthreads();
#pragma unroll
        for (int kc = 0; kc < 2; ++kc) {
            short8 afr[2], bfr[4];
#pragma unroll
            for (int mt = 0; mt < 2; ++mt)
                afr[mt] = *(const short8*)&As[wm * 32 + mt * 16 + m][kc * 32 + kb * 8];
#pragma unroll
            for (int nt = 0; nt < 4; ++nt)
                bfr[nt] = *(const short8*)&Bs[wn * 64 + nt * 16 + m][kc * 32 + kb * 8];
#pragma unroll
            for (int mt = 0; mt < 2; ++mt)
#pragma unroll
                for (int nt = 0; nt < 4; ++nt)
                    acc[mt][nt] = __builtin_amdgcn_mfma_f32_16x16x32_bf16(
                        afr[mt], bfr[nt], acc[mt][nt], 0, 0, 0);
        }
        __syncthreads();
    }

    // ---- epilogue ----
    const int rg = l >> 4;
    if (wn >= 2) {
        // v half: bias + relu -> bf16 store
#pragma unroll
        for (int mt = 0; mt < 2; ++mt) {
#pragma unroll
            for (int nt = 0; nt < 4; ++nt) {
                int col = wn * 64 + nt * 16 + m;        // 128..255
                float bsv = bias[col];
#pragma unroll
                for (int j = 0; j < 4; ++j) {
                    int rowl = wm * 32 + mt * 16 + rg * 4 + j;
                    float v = acc[mt][nt][j] + bsv;
                    v = v > 0.f ? v : 0.f;
                    vbuf[(size_t)(row0 + rowl) * AA_ + (col - 128)] = f2bf(v);
                }
            }
        }
    } else {
        // k half: s_r partial = sum_col relu(k)*u[col]
#pragma unroll
        for (int mt = 0; mt < 2; ++mt) {
            float p[4] = {0.f, 0.f, 0.f, 0.f};
#pragma unroll
            for (int nt = 0; nt < 4; ++nt) {
                int col = wn * 64 + nt * 16 + m;        // 0..127
                float bsv = bias[col];
                float uw = u[col];
#pragma unroll
                for (int j = 0; j < 4; ++j) {
                    float v = acc[mt][nt][j] + bsv;
                    v = v > 0.f ? v : 0.f;
                    p[j] += v * uw;
                }
            }
#pragma unroll
            for (int j = 0; j < 4; ++j) {
                p[j] += __shfl_xor(p[j], 1);
                p[j] += __shfl_xor(p[j], 2);
                p[j] += __shfl_xor(p[j], 4);
                p[j] += __shfl_xor(p[j], 8);
            }
            if (m == 0) {
#pragma unroll
                for (int j = 0; j < 4; ++j)
                    s_red[wm * 32 + mt * 16 + rg * 4 + j][wn] = p[j];
            }
        }
    }
    __syncthreads();
    if (t < 64) sout[row0 + t] = s_red[t][0] + s_red[t][1];
}

// ---------------- per-batch softmax over 4096 scores -> normalized weights
__global__ __launch_bounds__(1024)
void softmax_kernel(const float* __restrict__ s, float* __restrict__ wnorm) {
    __shared__ float red[17];
    int b = blockIdx.x, t = threadIdx.x;
    int l = t & 63, wv = t >> 6;
    const float inv_s = 0.08838834764831843f;  // 1/sqrt(128)
    float v[4], m = -1e30f;
#pragma unroll
    for (int i = 0; i < 4; ++i) {
        v[i] = s[b * 4096 + i * 1024 + t];
        m = fmaxf(m, v[i]);
    }
#pragma unroll
    for (int off = 1; off < 64; off <<= 1) m = fmaxf(m, __shfl_xor(m, off));
    if (l == 0) red[wv] = m;
    __syncthreads();
    if (t == 0) {
        float x = red[0];
        for (int i = 1; i < 16; ++i) x = fmaxf(x, red[i]);
        red[16] = x;
    }
    __syncthreads();
    float M = red[16];
    __syncthreads();
    float e[4], sum = 0.f;
#pragma unroll
    for (int i = 0; i < 4; ++i) {
        e[i] = __expf((v[i] - M) * inv_s);
        sum += e[i];
    }
#pragma unroll
    for (int off = 1; off < 64; off <<= 1) sum += __shfl_xor(sum, off);
    if (l == 0) red[wv] = sum;
    __syncthreads();
    if (t == 0) {
        float x = 0.f;
        for (int i = 0; i < 16; ++i) x += red[i];
        red[16] = 1.0f / x;
    }
    __syncthreads();
    float rS = red[16];
#pragma unroll
    for (int i = 0; i < 4; ++i)
        wnorm[b * 4096 + i * 1024 + t] = e[i] * rS;
}

// ---------------- num[b,d] = sum_j wnorm[b,j] * v[b,j,d]   (v in bf16)
__global__ __launch_bounds__(256)
void wsum_kernel(const ushort* __restrict__ vbuf, const float* __restrict__ wnorm,
                 float* __restrict__ num) {
    int b = blockIdx.x >> 3, ch = blockIdx.x & 7;
    int t = threadIdx.x, wv = t >> 6, l = t & 63;
    int rg = l >> 4, d8 = (l & 15) * 8;
    int rbase = b * 4096 + ch * 512;
    float acc[8] = {};
    for (int it = 0; it < 32; ++it) {
        int r = rbase + it * 16 + wv * 4 + rg;
        float wj = wnorm[r];
        short8 vv = *(const short8*)(vbuf + (size_t)r * AA_ + d8);
#pragma unroll
        for (int j = 0; j < 8; ++j)
            acc[j] += wj * bf2f((ushort)vv[j]);
    }
#pragma unroll
    for (int j = 0; j < 8; ++j) {
        acc[j] += __shfl_xor(acc[j], 16);
        acc[j] += __shfl_xor(acc[j], 32);
    }
    if (l < 16) {
#pragma unroll
        for (int j = 0; j < 8; ++j)
            atomicAdd(&num[b * AA_ + d8 + j], acc[j]);
    }
}

// ---------------- broadcast: out[b,i,:] = num[b,:]
__global__ void bcast_kernel(const float* __restrict__ num, float4* __restrict__ out) {
    int g = blockIdx.x * 256 + threadIdx.x;
    const float4* n4 = (const float4*)num;
    const int total4 = B_ * LD_ * AA_ / 4;  // 1048576
    for (int c = g; c < total4; c += 524288) {
        int flat = c * 4;
        int b = flat >> 19;          // / (4096*128)
        int d = flat & 127;
        out[c] = n4[b * 32 + (d >> 2)];
    }
}

extern "C" void kernel_launch(void* const* d_in, const int* in_sizes, int n_in,
                              void* d_out, int out_size, void* d_ws, size_t ws_size,
                              hipStream_t stream) {
    const float* enc = (const float*)d_in[0];
    // d_in[1]=decoder, d_in[2]=Wq, d_in[3]=bq, d_in[8]=Pw: provably unused
    // (softmax is shift-invariant in the q_term, which is constant per row)
    const float* Wk = (const float*)d_in[4];
    const float* bk = (const float*)d_in[5];
    const float* Wv = (const float*)d_in[6];
    const float* bv = (const float*)d_in[7];
    const float* Pu = (const float*)d_in[9];
    const float* pv = (const float*)d_in[10];

    char* ws = (char*)d_ws;
    ushort* wct   = (ushort*)(ws + WCT_OFF);
    float*  u     = (float*)(ws + U_OFF);
    float*  bias  = (float*)(ws + BIAS_OFF);
    float*  num   = (float*)(ws + NUM_OFF);
    float*  s     = (float*)(ws + S_OFF);
    float*  wnorm = (float*)(ws + WN_OFF);
    ushort* vbuf  = (ushort*)(ws + VB_OFF);

    prep_kernel<<<128, 256, 0, stream>>>(Wk, bk, Wv, bv, Pu, pv, wct, u, bias, num);
    gemm_fused<<<RTOT / 64, 512, 0, stream>>>(enc, wct, bias, u, vbuf, s);
    softmax_kernel<<<B_, 1024, 0, stream>>>(s, wnorm);
    wsum_kernel<<<B_ * 8, 256, 0, stream>>>(vbuf, wnorm, num);
    bcast_kernel<<<2048, 256, 0, stream>>>(num, (float4*)d_out);
}